// Round 8
// baseline (114.937 us; speedup 1.0000x reference)
//
#include <hip/hip_runtime.h>
#include <hip/hip_bf16.h>
#include <math.h>

typedef float4 f4;
typedef __attribute__((ext_vector_type(8))) short bf16x8;
typedef __attribute__((ext_vector_type(4))) float f32x4;

#define CD   768
#define SEQ  1024
#define NHD  12
#define DH   64

__device__ __forceinline__ ushort f2bf(float x) {
    union { __hip_bfloat16 h; ushort u; } v;
    v.h = __float2bfloat16(x);
    return v.u;
}
__device__ __forceinline__ unsigned pk2bf(float a, float b) {
    union { __hip_bfloat162 h; unsigned u; } v;
    v.h = __float22bfloat162_rn(make_float2(a, b));
    return v.u;
}
__device__ __forceinline__ float bf2f(short u) {
    union { unsigned u; float f; } v;
    v.u = ((unsigned)(ushort)u) << 16;
    return v.f;
}
__device__ __forceinline__ void gload_lds16(const ushort* g, ushort* l) {
    __builtin_amdgcn_global_load_lds((const __attribute__((address_space(1))) void*)g,
                                     (__attribute__((address_space(3))) void*)l, 16, 0, 0);
}

// ---------------- fp32 -> bf16 conversion pre-pass ---------------------------
// x, Wq, Wk, Wv -> row-major bf16; pw -> panel layout [k/64][n][k%64]
__global__ __launch_bounds__(256) void cvt_bf16_k(
    const float* __restrict__ x, const float* __restrict__ Wq,
    const float* __restrict__ Wk, const float* __restrict__ Wv,
    const float* __restrict__ pw, ushort* __restrict__ dst)
{
    const int idx = blockIdx.x * 256 + threadIdx.x;
    if (idx >= 1376256) return;
    const int e = idx << 2;
    if (e < 4915200) {
        const float* src; int off;
        if      (e < 3145728) { src = x;  off = e; }
        else if (e < 3735552) { src = Wq; off = e - 3145728; }
        else if (e < 4325376) { src = Wk; off = e - 3735552; }
        else                  { src = Wv; off = e - 4325376; }
        const f4 v = *(const f4*)(src + off);
        uint2 o;
        o.x = pk2bf(v.x, v.y);
        o.y = pk2bf(v.z, v.w);
        *(uint2*)(dst + e) = o;
    } else {
        const int off = e - 4915200;          // pw linear = n*768 + k
        const int n = off / CD, k = off - n * CD;
        const f4 v = *(const f4*)(pw + off);
        uint2 o;
        o.x = pk2bf(v.x, v.y);
        o.y = pk2bf(v.z, v.w);
        *(uint2*)(dst + 4915200 + ((size_t)(k >> 6) * CD + n) * 64 + (k & 63)) = o;
    }
}

// ---------------- QKV projection: bf16 MFMA GEMM ------------------------------
__global__ __launch_bounds__(256, 2) void qkv_mfma(
    const ushort* __restrict__ xbf,
    const ushort* __restrict__ wq, const ushort* __restrict__ wk, const ushort* __restrict__ wv,
    const float* __restrict__ bq, const float* __restrict__ bk, const float* __restrict__ bv,
    ushort* __restrict__ qbf, ushort* __restrict__ kbf, ushort* __restrict__ vbfT)
{
    __shared__ __align__(16) ushort As[16384];
    ushort* Bs = As + 8192;

    const int t = threadIdx.x;
    const int w = t >> 6, l = t & 63;
    const int lr = l & 15, lg = l >> 4;
    const int n0 = blockIdx.x << 7;
    const int m0 = blockIdx.y << 7;
    const int sel  = n0 / CD;
    const int nloc = n0 % CD;
    const ushort* Wb  = (sel == 0) ? wq : ((sel == 1) ? wk : wv);
    const float* bias = (sel == 0) ? bq : ((sel == 1) ? bk : bv);

    const int srow = (w << 3) + (l >> 3);
    const int scol = (l & 7) << 3;

    f32x4 acc[4][4];
    #pragma unroll
    for (int mi = 0; mi < 4; ++mi)
        #pragma unroll
        for (int ni = 0; ni < 4; ++ni) acc[mi][ni] = (f32x4){0.f, 0.f, 0.f, 0.f};

    const int mb = (w >> 1) << 6, nb = (w & 1) << 6;

    for (int kt = 0; kt < 12; ++kt) {
        const int kc = (kt << 6) + scol;
        __syncthreads();
        #pragma unroll
        for (int i = 0; i < 4; ++i) {
            const int row = (i << 5) + srow;
            gload_lds16(xbf + (size_t)(m0 + row) * CD + kc, &As[(i << 11) + (w << 9)]);
            gload_lds16(Wb + (size_t)(nloc + row) * CD + kc, &Bs[(i << 11) + (w << 9)]);
        }
        __syncthreads();
        #pragma unroll
        for (int kk = 0; kk < 2; ++kk) {
            bf16x8 af[4], bf[4];
            #pragma unroll
            for (int mi = 0; mi < 4; ++mi)
                af[mi] = *(const bf16x8*)&As[(mb + (mi << 4) + lr) * 64 + (kk << 5) + (lg << 3)];
            #pragma unroll
            for (int ni = 0; ni < 4; ++ni)
                bf[ni] = *(const bf16x8*)&Bs[(nb + (ni << 4) + lr) * 64 + (kk << 5) + (lg << 3)];
            #pragma unroll
            for (int mi = 0; mi < 4; ++mi)
                #pragma unroll
                for (int ni = 0; ni < 4; ++ni)
                    acc[mi][ni] = __builtin_amdgcn_mfma_f32_16x16x32_bf16(af[mi], bf[ni], acc[mi][ni], 0, 0, 0);
        }
    }

    __syncthreads();
    ushort* Ep = As + (w << 12);

    float bl[4];
    #pragma unroll
    for (int ni = 0; ni < 4; ++ni) bl[ni] = bias[nloc + nb + (ni << 4) + lr];

    if (sel < 2) {
        #pragma unroll
        for (int mi = 0; mi < 4; ++mi)
            #pragma unroll
            for (int ni = 0; ni < 4; ++ni)
                #pragma unroll
                for (int reg = 0; reg < 4; ++reg)
                    Ep[((mi << 4) + (lg << 2) + reg) * 64 + (ni << 4) + lr] =
                        f2bf(acc[mi][ni][reg] + bl[ni]);
    } else {
        // V: transpose + key-permute within 64-block: col=(mi*16+lg*4+reg) ->
        // col' = ((lg*4+reg)<<2) + mi
        #pragma unroll
        for (int mi = 0; mi < 4; ++mi)
            #pragma unroll
            for (int ni = 0; ni < 4; ++ni)
                #pragma unroll
                for (int reg = 0; reg < 4; ++reg)
                    Ep[((ni << 4) + lr) * 64 + (lg << 4) + (reg << 2) + mi] =
                        f2bf(acc[mi][ni][reg] + bl[ni]);
    }

    const int bi   = m0 >> 10;
    const int si0  = (m0 & 1023) + mb;
    const int head = (nloc + nb) >> 6;
    const int bn   = bi * NHD + head;
    const ushort* src = Ep + l * 64;
    if (sel < 2) {
        ushort* dbf = (sel == 0) ? qbf : kbf;
        ushort* dst = dbf + (((size_t)bn << 10) + si0 + l) * 64;
        #pragma unroll
        for (int c = 0; c < 8; ++c)
            *(bf16x8*)(dst + (c << 3)) = *(const bf16x8*)(src + (c << 3));
    } else {
        ushort* dst = vbfT + (((size_t)(bn * DH + l)) << 10) + si0;
        #pragma unroll
        for (int c = 0; c < 8; ++c)
            *(bf16x8*)(dst + (c << 3)) = *(const bf16x8*)(src + (c << 3));
    }
}

// ---------------- decomposed rel-pos bias tables (reads bf16 q) --------------
// rel_h output layout: rhb2[bn][qt(16)][ktp(16)][row(64)][2]
// rel_w output layout: rwb [bn][s][32]
__global__ __launch_bounds__(256) void rel_kernel(
    const ushort* __restrict__ qbf, const float* __restrict__ rph,
    const float* __restrict__ rpw,
    float* __restrict__ rhb2, float* __restrict__ rwb)
{
    __shared__ float qsl[32][65];
    __shared__ float rhsl[32][65];
    __shared__ float rwsl[63][65];
    const int t  = threadIdx.x;
    const int h  = blockIdx.x;
    const int bn = blockIdx.y;
    const ushort* qp = qbf + (((size_t)bn << 10) + h * 32) * DH;

    {
        const int r = t >> 3, c8 = (t & 7) << 3;
        const bf16x8 v = *(const bf16x8*)(qp + (size_t)r * DH + c8);
        #pragma unroll
        for (int j = 0; j < 8; ++j) qsl[r][c8 + j] = bf2f(v[j]);
    }
    #pragma unroll
    for (int it = 0; it < 2; ++it) {
        int idx = (it << 8) + t;
        if (idx < 32 * 16) {
            int r = idx >> 4, c4 = (idx & 15) << 2;
            f4 w2 = *(const f4*)(rph + (size_t)(h + r) * DH + c4);
            rhsl[r][c4+0]=w2.x; rhsl[r][c4+1]=w2.y; rhsl[r][c4+2]=w2.z; rhsl[r][c4+3]=w2.w;
        }
    }
    #pragma unroll
    for (int it = 0; it < 4; ++it) {
        int idx = (it << 8) + t;
        if (idx < 63 * 16) {
            int r = idx >> 4, c4 = (idx & 15) << 2;
            f4 w2 = *(const f4*)(rpw + (size_t)r * DH + c4);
            rwsl[r][c4+0]=w2.x; rwsl[r][c4+1]=w2.y; rwsl[r][c4+2]=w2.z; rwsl[r][c4+3]=w2.w;
        }
    }
    __syncthreads();

    float oh[4], ow[4];
    const int row32 = t >> 3;              // 0..31 (w coordinate)
    const int k20   = (t << 2) & 31;       // 0,4,...,28
    #pragma unroll
    for (int i = 0; i < 4; ++i) {
        const int k2 = k20 + i;
        const float* qr = &qsl[row32][0];
        const float* th = &rhsl[31 - k2][0];
        const float* tw = &rwsl[row32 - k2 + 31][0];
        float sh = 0.f, sw = 0.f;
        #pragma unroll 8
        for (int dd = 0; dd < DH; ++dd) {
            sh = fmaf(qr[dd], th[dd], sh);
            sw = fmaf(qr[dd], tw[dd], sw);
        }
        oh[i] = sh; ow[i] = sw;
    }
    // rel_h -> [bn][qt][ktp][row64][2]
    {
        const int s    = h * 32 + row32;
        const int qtl  = s >> 6, row64 = s & 63;
        const int ktp0 = k20 >> 1;
        float* base = rhb2 + ((size_t)(bn * 16 + qtl) * 16 + ktp0) * 128 + row64 * 2;
        *(float2*)base         = make_float2(oh[0], oh[1]);
        *(float2*)(base + 128) = make_float2(oh[2], oh[3]);
    }
    // rel_w -> [bn][s][32]
    {
        const size_t baseW = (((size_t)bn << 10) + h * 32 + row32) * 32 + k20;
        f4 vw; vw.x = ow[0]; vw.y = ow[1]; vw.z = ow[2]; vw.w = ow[3];
        *(f4*)(rwb + baseW) = vw;
    }
}

// ---------------- MFMA flash attention ---------------------------------------
// 128 q-rows per block (2 sub-tiles per wave) so K/V staging + LDS reads are
// amortized 2x. K,V via global_load_lds (linear dest, pre-swizzled source,
// XOR-swizzled reads); no-max softmax; row-sums via ones-MFMA; output written
// head-panel-major abf2[head][4096][64] for proj's panel staging.
__global__ __launch_bounds__(256, 2) void attn_mfma(
    const ushort* __restrict__ qbf, const ushort* __restrict__ kbf,
    const ushort* __restrict__ vbfT,
    const float* __restrict__ rhb2, const float* __restrict__ rwb,
    ushort* __restrict__ abf2)
{
    __shared__ __align__(16) ushort Kl[4096];     // [key][d] 64x64, swizzled
    __shared__ __align__(16) ushort Vt[4096];     // [d][key'] 64x64, swizzled
    __shared__ __align__(16) ushort Pl[4][16][72];

    const int t  = threadIdx.x;
    const int l  = t & 63, w = t >> 6;
    const int lr = l & 15, lg = l >> 4;
    const int qt = blockIdx.x, bn = blockIdx.y;
    const int q0 = qt << 7;                       // 128 rows per block

    bf16x8 qa[2][2];
    float rw_[2][4][2];
    const float* rhb_[2];
    #pragma unroll
    for (int s = 0; s < 2; ++s) {
        const ushort* qp = qbf + (((size_t)bn << 10) + q0 + (s << 6) + w * 16 + lr) * DH + lg * 8;
        qa[s][0] = *(const bf16x8*)qp;
        qa[s][1] = *(const bf16x8*)(qp + 32);
        #pragma unroll
        for (int reg = 0; reg < 4; ++reg) {
            const size_t rrow = ((size_t)bn << 10) + q0 + (s << 6) + w * 16 + lg * 4 + reg;
            rw_[s][reg][0] = rwb[(rrow << 5) + lr];
            rw_[s][reg][1] = rwb[(rrow << 5) + 16 + lr];
        }
        rhb_[s] = rhb2 + (size_t)(bn * 16 + qt * 2 + s) * 2048 + (w * 16 + lg * 4) * 2;
    }

    // staging geometry (same as proven R7 structure)
    const int i0   = w << 1;
    const int rsub = l >> 3;
    const int coff = ((l & 7) ^ rsub) << 3;
    const size_t kbase = ((size_t)bn << 16);
    const ushort* kp0 = kbf + kbase + (size_t)((i0 << 3) + rsub) * 64 + coff;
    const ushort* kp1 = kp0 + 512;
    const ushort* vp0 = vbfT + kbase + ((size_t)((i0 << 3) + rsub) << 10) + coff;
    const ushort* vp1 = vp0 + 8192;
    ushort* kl0 = &Kl[i0 << 9];
    ushort* vl0 = &Vt[i0 << 9];

    f32x4 oc[2][4];
    f32x4 sumc[2];
    #pragma unroll
    for (int s = 0; s < 2; ++s) {
        sumc[s] = (f32x4){0.f, 0.f, 0.f, 0.f};
        #pragma unroll
        for (int nf = 0; nf < 4; ++nf) oc[s][nf] = (f32x4){0.f, 0.f, 0.f, 0.f};
    }
    bf16x8 ones;
    #pragma unroll
    for (int i = 0; i < 8; ++i) ones[i] = (short)0x3F80;   // bf16 1.0

    const int s0c = lg ^ (lr & 7);   // swizzled 16B-chunk index for reads

    for (int kt = 0; kt < 16; ++kt) {
        f4 rh01[2], rh23[2];
        #pragma unroll
        for (int s = 0; s < 2; ++s) {
            rh01[s] = *(const f4*)(rhb_[s] + (kt << 7));
            rh23[s] = *(const f4*)(rhb_[s] + (kt << 7) + 4);
        }
        __syncthreads();                  // previous tile fully consumed
        gload_lds16(kp0 + (kt << 12), kl0);
        gload_lds16(kp1 + (kt << 12), kl0 + 512);
        gload_lds16(vp0 + (kt << 6), vl0);
        gload_lds16(vp1 + (kt << 6), vl0 + 512);
        __syncthreads();                  // staging complete

        #pragma unroll
        for (int s = 0; s < 2; ++s) {
            // ---- QK^T: S[16q x 64key] ----
            f32x4 sc[4];
            #pragma unroll
            for (int f = 0; f < 4; ++f) {
                f32x4 c = (f32x4){0.f, 0.f, 0.f, 0.f};
                const int rb = (f * 16 + lr) * 64;
                const bf16x8 kb0 = *(const bf16x8*)&Kl[rb + (s0c << 3)];
                const bf16x8 kb1 = *(const bf16x8*)&Kl[rb + ((s0c ^ 4) << 3)];
                c = __builtin_amdgcn_mfma_f32_16x16x32_bf16(qa[s][0], kb0, c, 0, 0, 0);
                c = __builtin_amdgcn_mfma_f32_16x16x32_bf16(qa[s][1], kb1, c, 0, 0, 0);
                sc[f] = c;
            }

            // ---- bias + exp (no max shift), pack P (key' = lr*4+f) ----
            #pragma unroll
            for (int reg = 0; reg < 4; ++reg) {
                const float rhx = (reg == 0) ? rh01[s].x : (reg == 1) ? rh01[s].z
                                 : (reg == 2) ? rh23[s].x : rh23[s].z;
                const float rhy = (reg == 0) ? rh01[s].y : (reg == 1) ? rh01[s].w
                                 : (reg == 2) ? rh23[s].y : rh23[s].w;
                const float e0 = __expf(fmaf(sc[0][reg], 0.125f, rhx + rw_[s][reg][0]));
                const float e1 = __expf(fmaf(sc[1][reg], 0.125f, rhx + rw_[s][reg][1]));
                const float e2 = __expf(fmaf(sc[2][reg], 0.125f, rhy + rw_[s][reg][0]));
                const float e3 = __expf(fmaf(sc[3][reg], 0.125f, rhy + rw_[s][reg][1]));
                uint2 pk;
                pk.x = pk2bf(e0, e1);
                pk.y = pk2bf(e2, e3);
                *(uint2*)&Pl[w][lg * 4 + reg][lr * 4] = pk;
            }

            // ---- P frags, row-sum MFMA, PV ----
            const bf16x8 pa0 = *(const bf16x8*)&Pl[w][lr][lg * 8];
            const bf16x8 pa1 = *(const bf16x8*)&Pl[w][lr][lg * 8 + 32];
            sumc[s] = __builtin_amdgcn_mfma_f32_16x16x32_bf16(pa0, ones, sumc[s], 0, 0, 0);
            sumc[s] = __builtin_amdgcn_mfma_f32_16x16x32_bf16(pa1, ones, sumc[s], 0, 0, 0);
            #pragma unroll
            for (int nf = 0; nf < 4; ++nf) {
                const int rb = (nf * 16 + lr) * 64;
                const bf16x8 vb0 = *(const bf16x8*)&Vt[rb + (s0c << 3)];
                const bf16x8 vb1 = *(const bf16x8*)&Vt[rb + ((s0c ^ 4) << 3)];
                oc[s][nf] = __builtin_amdgcn_mfma_f32_16x16x32_bf16(pa0, vb0, oc[s][nf], 0, 0, 0);
                oc[s][nf] = __builtin_amdgcn_mfma_f32_16x16x32_bf16(pa1, vb1, oc[s][nf], 0, 0, 0);
            }
        }
    }

    // ---- normalize, write abf2[head][4096][64] --------------------------
    const int bi = bn / NHD, hn = bn - bi * NHD;
    #pragma unroll
    for (int s = 0; s < 2; ++s) {
        #pragma unroll
        for (int reg = 0; reg < 4; ++reg) {
            const float inv = 1.f / sumc[s][reg];
            const int row = q0 + (s << 6) + w * 16 + lg * 4 + reg;
            ushort* dst = abf2 + ((size_t)hn * 4096 + (bi << 10) + row) * 64 + lr;
            union { unsigned u; ushort2 s2; } a, b;
            a.u = pk2bf(oc[s][0][reg] * inv, oc[s][1][reg] * inv);
            b.u = pk2bf(oc[s][2][reg] * inv, oc[s][3][reg] * inv);
            dst[0]  = a.s2.x;
            dst[16] = a.s2.y;
            dst[32] = b.s2.x;
            dst[48] = b.s2.y;
        }
    }
}

// ---------------- output projection: bf16 MFMA GEMM, BK=128 ------------------
// A = abf2 [panel p=k/64][m 4096][64]; B = pwbf2 [panel][n 768][64].
__global__ __launch_bounds__(256, 2) void proj_mfma(
    const ushort* __restrict__ abf2, const ushort* __restrict__ pwbf2,
    const float* __restrict__ pb, float* __restrict__ out)
{
    __shared__ __align__(16) ushort As[16384];    // [2 panels][128][64]
    __shared__ __align__(16) ushort Bs[16384];

    const int t = threadIdx.x;
    const int w = t >> 6, l = t & 63;
    const int lr = l & 15, lg = l >> 4;
    const int n0 = blockIdx.x << 7;
    const int m0 = blockIdx.y << 7;

    // staging: wave pairs (matrix, panel): w0=A/p0, w1=A/p1, w2=B/p0, w3=B/p1
    const int pnl  = w & 1;                     // panel within K-step
    const int isB  = w >> 1;
    const int srow = l >> 3;                    // 0..7 rows per instr
    const int scol = (l & 7) << 3;
    ushort* ldst = (isB ? Bs : As) + (pnl << 13);

    f32x4 acc[4][4];
    #pragma unroll
    for (int mi = 0; mi < 4; ++mi)
        #pragma unroll
        for (int ni = 0; ni < 4; ++ni) acc[mi][ni] = (f32x4){0.f, 0.f, 0.f, 0.f};

    const int mb = (w >> 1) << 6, nb = (w & 1) << 6;

    for (int kt = 0; kt < 6; ++kt) {
        const int p = (kt << 1) + pnl;
        const ushort* gsrc = isB
            ? pwbf2 + ((size_t)p * CD + n0 + srow) * 64 + scol
            : abf2 + ((size_t)p * 4096 + m0 + srow) * 64 + scol;
        __syncthreads();
        #pragma unroll
        for (int i = 0; i < 16; ++i)
            gload_lds16(gsrc + (size_t)(i << 3) * 64, ldst + (i << 9));
        __syncthreads();
        #pragma unroll
        for (int kk = 0; kk < 4; ++kk) {
            const ushort* Ap = As + ((kk >> 1) << 13);
            const ushort* Bp = Bs + ((kk >> 1) << 13);
            const int ko = ((kk & 1) << 5) + (lg << 3);
            bf16x8 af[4], bf[4];
            #pragma unroll
            for (int mi = 0; mi < 4; ++mi)
                af[mi] = *(const bf16x8*)&Ap[(mb + (mi << 4) + lr) * 64 + ko];
            #pragma unroll
            for (int ni = 0; ni < 4; ++ni)
                bf[ni] = *(const bf16x8*)&Bp[(nb + (ni << 4) + lr) * 64 + ko];
            #pragma unroll
            for (int mi = 0; mi < 4; ++mi)
                #pragma unroll
                for (int ni = 0; ni < 4; ++ni)
                    acc[mi][ni] = __builtin_amdgcn_mfma_f32_16x16x32_bf16(af[mi], bf[ni], acc[mi][ni], 0, 0, 0);
        }
    }

    float bl[4];
    #pragma unroll
    for (int ni = 0; ni < 4; ++ni) bl[ni] = pb[n0 + nb + (ni << 4) + lr];
    #pragma unroll
    for (int mi = 0; mi < 4; ++mi)
        #pragma unroll
        for (int ni = 0; ni < 4; ++ni)
            #pragma unroll
            for (int reg = 0; reg < 4; ++reg)
                out[(size_t)(m0 + mb + (mi << 4) + (lg << 2) + reg) * CD
                    + n0 + nb + (ni << 4) + lr] = acc[mi][ni][reg] + bl[ni];
}

extern "C" void kernel_launch(void* const* d_in, const int* in_sizes, int n_in,
                              void* d_out, int out_size, void* d_ws, size_t ws_size,
                              hipStream_t stream) {
    (void)in_sizes; (void)n_in; (void)out_size; (void)ws_size;
    const float* x   = (const float*)d_in[0];
    const float* Wq  = (const float*)d_in[1];
    const float* Wk  = (const float*)d_in[2];
    const float* Wv  = (const float*)d_in[3];
    const float* bq  = (const float*)d_in[4];
    const float* bk  = (const float*)d_in[5];
    const float* bv  = (const float*)d_in[6];
    const float* rph = (const float*)d_in[7];
    const float* rpw = (const float*)d_in[8];
    const float* pw  = (const float*)d_in[9];
    const float* pb  = (const float*)d_in[10];
    float* out = (float*)d_out;

    ushort* cvt  = (ushort*)d_ws;
    ushort* xbf  = cvt;
    ushort* wqbf = cvt + 3145728;
    ushort* wkbf = wqbf + 589824;
    ushort* wvbf = wkbf + 589824;
    ushort* pwbf = wvbf + 589824;      // panel layout [k/64][768][64]
    ushort* qbf  = pwbf + 589824;
    ushort* kbf  = qbf  + 3145728;
    ushort* vbfT = kbf  + 3145728;
    ushort* abf2 = vbfT + 3145728;     // [head][4096][64]
    float*  rhb2 = (float*)(abf2 + 3145728);
    float*  rwb  = rhb2 + 1572864;

    hipLaunchKernelGGL(cvt_bf16_k, dim3(5376), dim3(256), 0, stream,
                       x, Wq, Wk, Wv, pw, cvt);
    hipLaunchKernelGGL(qkv_mfma, dim3(18, 32), dim3(256), 0, stream,
                       xbf, wqbf, wkbf, wvbf, bq, bk, bv, qbf, kbf, vbfT);
    hipLaunchKernelGGL(rel_kernel, dim3(32, 48), dim3(256), 0, stream,
                       qbf, rph, rpw, rhb2, rwb);
    hipLaunchKernelGGL(attn_mfma, dim3(8, 48), dim3(256), 0, stream,
                       qbf, kbf, vbfT, rhb2, rwb, abf2);
    hipLaunchKernelGGL(proj_mfma, dim3(6, 32), dim3(256), 0, stream,
                       abf2, pwbf, pb, out);
}

// Round 9
// 109.559 us; speedup vs baseline: 1.0491x; 1.0491x over previous
//
#include <hip/hip_runtime.h>
#include <hip/hip_bf16.h>
#include <math.h>

typedef float4 f4;
typedef __attribute__((ext_vector_type(8))) short bf16x8;
typedef __attribute__((ext_vector_type(4))) float f32x4;

#define CD   768
#define SEQ  1024
#define NHD  12
#define DH   64

__device__ __forceinline__ ushort f2bf(float x) {
    union { __hip_bfloat16 h; ushort u; } v;
    v.h = __float2bfloat16(x);
    return v.u;
}
__device__ __forceinline__ unsigned pk2bf(float a, float b) {
    union { __hip_bfloat162 h; unsigned u; } v;
    v.h = __float22bfloat162_rn(make_float2(a, b));
    return v.u;
}
__device__ __forceinline__ float bf2f(short u) {
    union { unsigned u; float f; } v;
    v.u = ((unsigned)(ushort)u) << 16;
    return v.f;
}
__device__ __forceinline__ void gload_lds16(const ushort* g, ushort* l) {
    __builtin_amdgcn_global_load_lds((const __attribute__((address_space(1))) void*)g,
                                     (__attribute__((address_space(3))) void*)l, 16, 0, 0);
}

// ---------------- fp32 -> bf16 conversion pre-pass ---------------------------
// x, Wq, Wk, Wv -> row-major bf16; pw -> panel layout [k/64][n][k%64]
__global__ __launch_bounds__(256) void cvt_bf16_k(
    const float* __restrict__ x, const float* __restrict__ Wq,
    const float* __restrict__ Wk, const float* __restrict__ Wv,
    const float* __restrict__ pw, ushort* __restrict__ dst)
{
    const int idx = blockIdx.x * 256 + threadIdx.x;
    if (idx >= 1376256) return;
    const int e = idx << 2;
    if (e < 4915200) {
        const float* src; int off;
        if      (e < 3145728) { src = x;  off = e; }
        else if (e < 3735552) { src = Wq; off = e - 3145728; }
        else if (e < 4325376) { src = Wk; off = e - 3735552; }
        else                  { src = Wv; off = e - 4325376; }
        const f4 v = *(const f4*)(src + off);
        uint2 o;
        o.x = pk2bf(v.x, v.y);
        o.y = pk2bf(v.z, v.w);
        *(uint2*)(dst + e) = o;
    } else {
        const int off = e - 4915200;          // pw linear = n*768 + k
        const int n = off / CD, k = off - n * CD;
        const f4 v = *(const f4*)(pw + off);
        uint2 o;
        o.x = pk2bf(v.x, v.y);
        o.y = pk2bf(v.z, v.w);
        *(uint2*)(dst + 4915200 + ((size_t)(k >> 6) * CD + n) * 64 + (k & 63)) = o;
    }
}

// ---------------- QKV projection: bf16 MFMA GEMM, 2-phase dbuf ----------------
__global__ __launch_bounds__(256, 2) void qkv_mfma(
    const ushort* __restrict__ xbf,
    const ushort* __restrict__ wq, const ushort* __restrict__ wk, const ushort* __restrict__ wv,
    const float* __restrict__ bq, const float* __restrict__ bk, const float* __restrict__ bv,
    ushort* __restrict__ qbf, ushort* __restrict__ kbf, ushort* __restrict__ vbfT)
{
    __shared__ __align__(16) ushort Sq[32768];   // buf b: A at b*16384, B at +8192

    const int t = threadIdx.x;
    const int w = t >> 6, l = t & 63;
    const int lr = l & 15, lg = l >> 4;
    const int n0 = blockIdx.x << 7;
    const int m0 = blockIdx.y << 7;
    const int sel  = n0 / CD;
    const int nloc = n0 % CD;
    const ushort* Wb  = (sel == 0) ? wq : ((sel == 1) ? wk : wv);
    const float* bias = (sel == 0) ? bq : ((sel == 1) ? bk : bv);

    const int srow = (w << 3) + (l >> 3);
    const int scol = (l & 7) << 3;
    const ushort* Agl = xbf + (size_t)(m0 + srow) * CD + scol;
    const ushort* Bgl = Wb + (size_t)(nloc + srow) * CD + scol;

    f32x4 acc[4][4];
    #pragma unroll
    for (int mi = 0; mi < 4; ++mi)
        #pragma unroll
        for (int ni = 0; ni < 4; ++ni) acc[mi][ni] = (f32x4){0.f, 0.f, 0.f, 0.f};

    const int mb = (w >> 1) << 6, nb = (w & 1) << 6;

    // prologue: stage K-step 0 into buf 0
    #pragma unroll
    for (int i = 0; i < 4; ++i) {
        gload_lds16(Agl + (size_t)(i << 5) * CD, &Sq[(i << 11) + (w << 9)]);
        gload_lds16(Bgl + (size_t)(i << 5) * CD, &Sq[8192 + (i << 11) + (w << 9)]);
    }
    __syncthreads();

    for (int kt = 0; kt < 12; ++kt) {
        const int cb = (kt & 1) << 14;
        if (kt < 11) {
            const int nbuf = ((kt + 1) & 1) << 14;
            const int kc = (kt + 1) << 6;
            #pragma unroll
            for (int i = 0; i < 4; ++i) {
                gload_lds16(Agl + (size_t)(i << 5) * CD + kc, &Sq[nbuf + (i << 11) + (w << 9)]);
                gload_lds16(Bgl + (size_t)(i << 5) * CD + kc, &Sq[nbuf + 8192 + (i << 11) + (w << 9)]);
            }
        }
        #pragma unroll
        for (int kk = 0; kk < 2; ++kk) {
            bf16x8 af[4], bf[4];
            #pragma unroll
            for (int mi = 0; mi < 4; ++mi)
                af[mi] = *(const bf16x8*)&Sq[cb + (mb + (mi << 4) + lr) * 64 + (kk << 5) + (lg << 3)];
            #pragma unroll
            for (int ni = 0; ni < 4; ++ni)
                bf[ni] = *(const bf16x8*)&Sq[cb + 8192 + (nb + (ni << 4) + lr) * 64 + (kk << 5) + (lg << 3)];
            #pragma unroll
            for (int mi = 0; mi < 4; ++mi)
                #pragma unroll
                for (int ni = 0; ni < 4; ++ni)
                    acc[mi][ni] = __builtin_amdgcn_mfma_f32_16x16x32_bf16(af[mi], bf[ni], acc[mi][ni], 0, 0, 0);
        }
        __syncthreads();
    }

    ushort* Ep = Sq + (w << 12);

    float bl[4];
    #pragma unroll
    for (int ni = 0; ni < 4; ++ni) bl[ni] = bias[nloc + nb + (ni << 4) + lr];

    if (sel < 2) {
        #pragma unroll
        for (int mi = 0; mi < 4; ++mi)
            #pragma unroll
            for (int ni = 0; ni < 4; ++ni)
                #pragma unroll
                for (int reg = 0; reg < 4; ++reg)
                    Ep[((mi << 4) + (lg << 2) + reg) * 64 + (ni << 4) + lr] =
                        f2bf(acc[mi][ni][reg] + bl[ni]);
    } else {
        // V: transpose + key-permute within 64-block
        #pragma unroll
        for (int mi = 0; mi < 4; ++mi)
            #pragma unroll
            for (int ni = 0; ni < 4; ++ni)
                #pragma unroll
                for (int reg = 0; reg < 4; ++reg)
                    Ep[((ni << 4) + lr) * 64 + (lg << 4) + (reg << 2) + mi] =
                        f2bf(acc[mi][ni][reg] + bl[ni]);
    }

    const int bi   = m0 >> 10;
    const int si0  = (m0 & 1023) + mb;
    const int head = (nloc + nb) >> 6;
    const int bn   = bi * NHD + head;
    const ushort* src = Ep + l * 64;
    if (sel < 2) {
        ushort* dbf = (sel == 0) ? qbf : kbf;
        ushort* dst = dbf + (((size_t)bn << 10) + si0 + l) * 64;
        #pragma unroll
        for (int c = 0; c < 8; ++c)
            *(bf16x8*)(dst + (c << 3)) = *(const bf16x8*)(src + (c << 3));
    } else {
        ushort* dst = vbfT + (((size_t)(bn * DH + l)) << 10) + si0;
        #pragma unroll
        for (int c = 0; c < 8; ++c)
            *(bf16x8*)(dst + (c << 3)) = *(const bf16x8*)(src + (c << 3));
    }
}

// ---------------- decomposed rel-pos bias tables (reads bf16 q) --------------
__global__ __launch_bounds__(256) void rel_kernel(
    const ushort* __restrict__ qbf, const float* __restrict__ rph,
    const float* __restrict__ rpw,
    float* __restrict__ rhb2, float* __restrict__ rwb)
{
    __shared__ float qsl[32][65];
    __shared__ float rhsl[32][65];
    __shared__ float rwsl[63][65];
    const int t  = threadIdx.x;
    const int h  = blockIdx.x;
    const int bn = blockIdx.y;
    const ushort* qp = qbf + (((size_t)bn << 10) + h * 32) * DH;

    {
        const int r = t >> 3, c8 = (t & 7) << 3;
        const bf16x8 v = *(const bf16x8*)(qp + (size_t)r * DH + c8);
        #pragma unroll
        for (int j = 0; j < 8; ++j) qsl[r][c8 + j] = bf2f(v[j]);
    }
    #pragma unroll
    for (int it = 0; it < 2; ++it) {
        int idx = (it << 8) + t;
        if (idx < 32 * 16) {
            int r = idx >> 4, c4 = (idx & 15) << 2;
            f4 w2 = *(const f4*)(rph + (size_t)(h + r) * DH + c4);
            rhsl[r][c4+0]=w2.x; rhsl[r][c4+1]=w2.y; rhsl[r][c4+2]=w2.z; rhsl[r][c4+3]=w2.w;
        }
    }
    #pragma unroll
    for (int it = 0; it < 4; ++it) {
        int idx = (it << 8) + t;
        if (idx < 63 * 16) {
            int r = idx >> 4, c4 = (idx & 15) << 2;
            f4 w2 = *(const f4*)(rpw + (size_t)r * DH + c4);
            rwsl[r][c4+0]=w2.x; rwsl[r][c4+1]=w2.y; rwsl[r][c4+2]=w2.z; rwsl[r][c4+3]=w2.w;
        }
    }
    __syncthreads();

    float oh[4], ow[4];
    const int row32 = t >> 3;              // 0..31 (w coordinate)
    const int k20   = (t << 2) & 31;       // 0,4,...,28
    #pragma unroll
    for (int i = 0; i < 4; ++i) {
        const int k2 = k20 + i;
        const float* qr = &qsl[row32][0];
        const float* th = &rhsl[31 - k2][0];
        const float* tw = &rwsl[row32 - k2 + 31][0];
        float sh = 0.f, sw = 0.f;
        #pragma unroll 8
        for (int dd = 0; dd < DH; ++dd) {
            sh = fmaf(qr[dd], th[dd], sh);
            sw = fmaf(qr[dd], tw[dd], sw);
        }
        oh[i] = sh; ow[i] = sw;
    }
    // rel_h -> [bn][qt][ktp][row64][2]
    {
        const int s    = h * 32 + row32;
        const int qtl  = s >> 6, row64 = s & 63;
        const int ktp0 = k20 >> 1;
        float* base = rhb2 + ((size_t)(bn * 16 + qtl) * 16 + ktp0) * 128 + row64 * 2;
        *(float2*)base         = make_float2(oh[0], oh[1]);
        *(float2*)(base + 128) = make_float2(oh[2], oh[3]);
    }
    // rel_w -> [bn][s][32]
    {
        const size_t baseW = (((size_t)bn << 10) + h * 32 + row32) * 32 + k20;
        f4 vw; vw.x = ow[0]; vw.y = ow[1]; vw.z = ow[2]; vw.w = ow[3];
        *(f4*)(rwb + baseW) = vw;
    }
}

// ---------------- MFMA flash attention, 2-phase K/V double-buffer -------------
// 64 q-rows/block (grid 768, 3 blocks/CU). Stage NEXT K/V tile before computing
// current; ONE barrier per tile (vmcnt drain overlapped with compute).
__global__ __launch_bounds__(256, 3) void attn_mfma(
    const ushort* __restrict__ qbf, const ushort* __restrict__ kbf,
    const ushort* __restrict__ vbfT,
    const float* __restrict__ rhb2, const float* __restrict__ rwb,
    ushort* __restrict__ abf2)
{
    __shared__ __align__(16) ushort KV[2][8192];  // [buf][ K:0..4095 | V:4096.. ]
    __shared__ __align__(16) ushort Pl[4][16][72];

    const int t  = threadIdx.x;
    const int l  = t & 63, w = t >> 6;
    const int lr = l & 15, lg = l >> 4;
    const int qt = blockIdx.x, bn = blockIdx.y;
    const int q0 = qt << 6;

    const ushort* qp = qbf + (((size_t)bn << 10) + q0 + w * 16 + lr) * DH + lg * 8;
    const bf16x8 qa0 = *(const bf16x8*)qp;
    const bf16x8 qa1 = *(const bf16x8*)(qp + 32);

    float rw_[4][2];
    #pragma unroll
    for (int reg = 0; reg < 4; ++reg) {
        const size_t rrow = ((size_t)bn << 10) + q0 + w * 16 + lg * 4 + reg;
        rw_[reg][0] = rwb[(rrow << 5) + lr];
        rw_[reg][1] = rwb[(rrow << 5) + 16 + lr];
    }
    const float* rhbase = rhb2 + (size_t)(bn * 16 + qt) * 2048 + (w * 16 + lg * 4) * 2;

    // staging geometry (proven R7 structure, dbuf dest)
    const int i0   = w << 1;
    const int rsub = l >> 3;
    const int coff = ((l & 7) ^ rsub) << 3;
    const size_t kbase = ((size_t)bn << 16);
    const ushort* kp0 = kbf + kbase + (size_t)((i0 << 3) + rsub) * 64 + coff;
    const ushort* kp1 = kp0 + 512;
    const ushort* vp0 = vbfT + kbase + ((size_t)((i0 << 3) + rsub) << 10) + coff;
    const ushort* vp1 = vp0 + 8192;
    const int lds0 = i0 << 9;

    f32x4 oc[4];
    #pragma unroll
    for (int nf = 0; nf < 4; ++nf) oc[nf] = (f32x4){0.f, 0.f, 0.f, 0.f};
    f32x4 sumc = (f32x4){0.f, 0.f, 0.f, 0.f};
    bf16x8 ones;
    #pragma unroll
    for (int i = 0; i < 8; ++i) ones[i] = (short)0x3F80;   // bf16 1.0

    const int s0c = lg ^ (lr & 7);   // swizzled 16B-chunk index for reads

    // prologue: stage tile 0 into buf 0
    gload_lds16(kp0, &KV[0][lds0]);
    gload_lds16(kp1, &KV[0][lds0 + 512]);
    gload_lds16(vp0, &KV[0][4096 + lds0]);
    gload_lds16(vp1, &KV[0][4096 + lds0 + 512]);
    __syncthreads();

    for (int kt = 0; kt < 16; ++kt) {
        const int cur = kt & 1;
        if (kt < 15) {
            ushort* nb_ = &KV[cur ^ 1][0];
            gload_lds16(kp0 + ((kt + 1) << 12), nb_ + lds0);
            gload_lds16(kp1 + ((kt + 1) << 12), nb_ + lds0 + 512);
            gload_lds16(vp0 + ((kt + 1) << 6), nb_ + 4096 + lds0);
            gload_lds16(vp1 + ((kt + 1) << 6), nb_ + 4096 + lds0 + 512);
        }
        const ushort* Kl = &KV[cur][0];
        const ushort* Vt = &KV[cur][4096];
        const f4 rh01 = *(const f4*)(rhbase + (kt << 7));
        const f4 rh23 = *(const f4*)(rhbase + (kt << 7) + 4);

        // ---- QK^T: S[16q x 64key] per wave ----
        f32x4 sc[4];
        #pragma unroll
        for (int f = 0; f < 4; ++f) {
            f32x4 c = (f32x4){0.f, 0.f, 0.f, 0.f};
            const int rb = (f * 16 + lr) * 64;
            const bf16x8 kb0 = *(const bf16x8*)&Kl[rb + (s0c << 3)];
            const bf16x8 kb1 = *(const bf16x8*)&Kl[rb + ((s0c ^ 4) << 3)];
            c = __builtin_amdgcn_mfma_f32_16x16x32_bf16(qa0, kb0, c, 0, 0, 0);
            c = __builtin_amdgcn_mfma_f32_16x16x32_bf16(qa1, kb1, c, 0, 0, 0);
            sc[f] = c;
        }

        // ---- bias + exp (no max shift), pack P (key' = lr*4+f) ----
        #pragma unroll
        for (int reg = 0; reg < 4; ++reg) {
            const float rhx = (reg == 0) ? rh01.x : (reg == 1) ? rh01.z
                             : (reg == 2) ? rh23.x : rh23.z;
            const float rhy = (reg == 0) ? rh01.y : (reg == 1) ? rh01.w
                             : (reg == 2) ? rh23.y : rh23.w;
            const float e0 = __expf(fmaf(sc[0][reg], 0.125f, rhx + rw_[reg][0]));
            const float e1 = __expf(fmaf(sc[1][reg], 0.125f, rhx + rw_[reg][1]));
            const float e2 = __expf(fmaf(sc[2][reg], 0.125f, rhy + rw_[reg][0]));
            const float e3 = __expf(fmaf(sc[3][reg], 0.125f, rhy + rw_[reg][1]));
            uint2 pk;
            pk.x = pk2bf(e0, e1);
            pk.y = pk2bf(e2, e3);
            *(uint2*)&Pl[w][lg * 4 + reg][lr * 4] = pk;
        }

        // ---- P frags, row-sum MFMA, PV ----
        const bf16x8 pa0 = *(const bf16x8*)&Pl[w][lr][lg * 8];
        const bf16x8 pa1 = *(const bf16x8*)&Pl[w][lr][lg * 8 + 32];
        sumc = __builtin_amdgcn_mfma_f32_16x16x32_bf16(pa0, ones, sumc, 0, 0, 0);
        sumc = __builtin_amdgcn_mfma_f32_16x16x32_bf16(pa1, ones, sumc, 0, 0, 0);
        #pragma unroll
        for (int nf = 0; nf < 4; ++nf) {
            const int rb = (nf * 16 + lr) * 64;
            const bf16x8 vb0 = *(const bf16x8*)&Vt[rb + (s0c << 3)];
            const bf16x8 vb1 = *(const bf16x8*)&Vt[rb + ((s0c ^ 4) << 3)];
            oc[nf] = __builtin_amdgcn_mfma_f32_16x16x32_bf16(pa0, vb0, oc[nf], 0, 0, 0);
            oc[nf] = __builtin_amdgcn_mfma_f32_16x16x32_bf16(pa1, vb1, oc[nf], 0, 0, 0);
        }
        __syncthreads();
    }

    // ---- normalize, write abf2[head][4096][64] -------------------------------
    const int bi = bn / NHD, hn = bn - bi * NHD;
    #pragma unroll
    for (int reg = 0; reg < 4; ++reg) {
        const float inv = 1.f / sumc[reg];
        const int row = q0 + w * 16 + lg * 4 + reg;
        ushort* dst = abf2 + ((size_t)hn * 4096 + (bi << 10) + row) * 64 + lr;
        union { unsigned u; ushort2 s2; } a, b;
        a.u = pk2bf(oc[0][reg] * inv, oc[1][reg] * inv);
        b.u = pk2bf(oc[2][reg] * inv, oc[3][reg] * inv);
        dst[0]  = a.s2.x;
        dst[16] = a.s2.y;
        dst[32] = b.s2.x;
        dst[48] = b.s2.y;
    }
}

// ---------------- output projection: bf16 MFMA GEMM, 2-phase dbuf -------------
// A = abf2 [panel p][4096][64]; B = pwbf2 [panel][768][64]; BK=64.
__global__ __launch_bounds__(256, 2) void proj_mfma(
    const ushort* __restrict__ abf2, const ushort* __restrict__ pwbf2,
    const float* __restrict__ pb, float* __restrict__ out)
{
    __shared__ __align__(16) ushort Sp[32768];   // buf b: A at b*16384, B at +8192

    const int t = threadIdx.x;
    const int w = t >> 6, l = t & 63;
    const int lr = l & 15, lg = l >> 4;
    const int n0 = blockIdx.x << 7;
    const int m0 = blockIdx.y << 7;

    const int srow = (w << 3) + (l >> 3);
    const int scol = (l & 7) << 3;
    const ushort* Agl = abf2 + (size_t)(m0 + srow) * 64 + scol;   // + p*4096*64
    const ushort* Bgl = pwbf2 + (size_t)(n0 + srow) * 64 + scol;  // + p*768*64

    f32x4 acc[4][4];
    #pragma unroll
    for (int mi = 0; mi < 4; ++mi)
        #pragma unroll
        for (int ni = 0; ni < 4; ++ni) acc[mi][ni] = (f32x4){0.f, 0.f, 0.f, 0.f};

    const int mb = (w >> 1) << 6, nb = (w & 1) << 6;

    #pragma unroll
    for (int i = 0; i < 4; ++i) {
        gload_lds16(Agl + (size_t)(i << 5) * 64, &Sp[(i << 11) + (w << 9)]);
        gload_lds16(Bgl + (size_t)(i << 5) * 64, &Sp[8192 + (i << 11) + (w << 9)]);
    }
    __syncthreads();

    for (int kt = 0; kt < 12; ++kt) {
        const int cb = (kt & 1) << 14;
        if (kt < 11) {
            const int nbuf = ((kt + 1) & 1) << 14;
            #pragma unroll
            for (int i = 0; i < 4; ++i) {
                gload_lds16(Agl + ((size_t)(kt + 1) * 4096 + (i << 5)) * 64,
                            &Sp[nbuf + (i << 11) + (w << 9)]);
                gload_lds16(Bgl + ((size_t)(kt + 1) * CD + (i << 5)) * 64,
                            &Sp[nbuf + 8192 + (i << 11) + (w << 9)]);
            }
        }
        #pragma unroll
        for (int kk = 0; kk < 2; ++kk) {
            bf16x8 af[4], bf[4];
            #pragma unroll
            for (int mi = 0; mi < 4; ++mi)
                af[mi] = *(const bf16x8*)&Sp[cb + (mb + (mi << 4) + lr) * 64 + (kk << 5) + (lg << 3)];
            #pragma unroll
            for (int ni = 0; ni < 4; ++ni)
                bf[ni] = *(const bf16x8*)&Sp[cb + 8192 + (nb + (ni << 4) + lr) * 64 + (kk << 5) + (lg << 3)];
            #pragma unroll
            for (int mi = 0; mi < 4; ++mi)
                #pragma unroll
                for (int ni = 0; ni < 4; ++ni)
                    acc[mi][ni] = __builtin_amdgcn_mfma_f32_16x16x32_bf16(af[mi], bf[ni], acc[mi][ni], 0, 0, 0);
        }
        __syncthreads();
    }

    float bl[4];
    #pragma unroll
    for (int ni = 0; ni < 4; ++ni) bl[ni] = pb[n0 + nb + (ni << 4) + lr];
    #pragma unroll
    for (int mi = 0; mi < 4; ++mi)
        #pragma unroll
        for (int ni = 0; ni < 4; ++ni)
            #pragma unroll
            for (int reg = 0; reg < 4; ++reg)
                out[(size_t)(m0 + mb + (mi << 4) + (lg << 2) + reg) * CD
                    + n0 + nb + (ni << 4) + lr] = acc[mi][ni][reg] + bl[ni];
}

extern "C" void kernel_launch(void* const* d_in, const int* in_sizes, int n_in,
                              void* d_out, int out_size, void* d_ws, size_t ws_size,
                              hipStream_t stream) {
    (void)in_sizes; (void)n_in; (void)out_size; (void)ws_size;
    const float* x   = (const float*)d_in[0];
    const float* Wq  = (const float*)d_in[1];
    const float* Wk  = (const float*)d_in[2];
    const float* Wv  = (const float*)d_in[3];
    const float* bq  = (const float*)d_in[4];
    const float* bk  = (const float*)d_in[5];
    const float* bv  = (const float*)d_in[6];
    const float* rph = (const float*)d_in[7];
    const float* rpw = (const float*)d_in[8];
    const float* pw  = (const float*)d_in[9];
    const float* pb  = (const float*)d_in[10];
    float* out = (float*)d_out;

    ushort* cvt  = (ushort*)d_ws;
    ushort* xbf  = cvt;
    ushort* wqbf = cvt + 3145728;
    ushort* wkbf = wqbf + 589824;
    ushort* wvbf = wkbf + 589824;
    ushort* pwbf = wvbf + 589824;      // panel layout [k/64][768][64]
    ushort* qbf  = pwbf + 589824;
    ushort* kbf  = qbf  + 3145728;
    ushort* vbfT = kbf  + 3145728;
    ushort* abf2 = vbfT + 3145728;     // [head][4096][64]
    float*  rhb2 = (float*)(abf2 + 3145728);
    float*  rwb  = rhb2 + 1572864;

    hipLaunchKernelGGL(cvt_bf16_k, dim3(5376), dim3(256), 0, stream,
                       x, Wq, Wk, Wv, pw, cvt);
    hipLaunchKernelGGL(qkv_mfma, dim3(18, 32), dim3(256), 0, stream,
                       xbf, wqbf, wkbf, wvbf, bq, bk, bv, qbf, kbf, vbfT);
    hipLaunchKernelGGL(rel_kernel, dim3(32, 48), dim3(256), 0, stream,
                       qbf, rph, rpw, rhb2, rwb);
    hipLaunchKernelGGL(attn_mfma, dim3(16, 48), dim3(256), 0, stream,
                       qbf, kbf, vbfT, rhb2, rwb, abf2);
    hipLaunchKernelGGL(proj_mfma, dim3(6, 32), dim3(256), 0, stream,
                       abf2, pwbf, pb, out);
}